// Round 5
// baseline (760.502 us; speedup 1.0000x reference)
//
#include <hip/hip_runtime.h>
#include <hip/hip_bf16.h>

// SwinTransformerEncoder on gfx950.
// H=W=64, C=256, HEADS=8 (d=32), WS=8, N=64 tok/window, NW=64, B=8, DEPTH=2, HIDDEN=1024.
// Inputs fp32 (runtime probe also supports bf16-cast). OUTPUT fp32 (round-4 finding:
// bit-exact 7.359375 error across different schedules == bf16-pair misread as fp32).
// Residual fp32 in ws.
//
// Workspace (99.0 MiB total):
//   xf   fp32 [8*4096*256]   @ 0          (32 MiB)  residual stream
//   bufQ bf16 [32768*768]    @ 33554432   (48 MiB)  qkv; later fc1 hidden halves [32768*512]
//   bufB bf16 [32768*256]    @ 83886080   (16 MiB)  LN out, then attn out
//   wT   bf16 [2*786432]     @ 100663296  (3 MiB)   transposed weights
//   mode int                 @ 103809024  (4 B)     input-dtype flag (1=bf16, 0=fp32)

typedef __hip_bfloat16 bf16;
typedef unsigned short u16;
typedef unsigned int u32;
typedef short short8 __attribute__((ext_vector_type(8)));
typedef float floatx4 __attribute__((ext_vector_type(4)));

#define DEVI static __device__ __forceinline__

DEVI float lo16(u32 u) { union { u32 i; float f; } x; x.i = u << 16; return x.f; }
DEVI float hi16(u32 u) { union { u32 i; float f; } x; x.i = u & 0xffff0000u; return x.f; }
DEVI float b2f(u16 u) { union { u32 i; float f; } x; x.i = ((u32)u) << 16; return x.f; }
DEVI u16 f2b(float f) {  // round-to-nearest-even
  union { float f; u32 i; } x; x.f = f;
  u32 r = x.i + 0x7fffu + ((x.i >> 16) & 1u);
  return (u16)(r >> 16);
}
DEVI float in_elem(const void* p, size_t i, int m) {
  return m ? b2f(((const u16*)p)[i]) : ((const float*)p)[i];
}

// ---------------- dtype probe (ln1_g is all-ones) ----------------
__global__ void k_detect(const u32* __restrict__ ln1g, int* __restrict__ mode) {
  if (threadIdx.x == 0 && blockIdx.x == 0)
    *mode = (ln1g[0] == 0x3F803F80u) ? 1 : 0;
}

// ---------------- ingest x -> fp32 residual ----------------
__global__ void k_ingest(const void* __restrict__ xin, float2* __restrict__ out,
                         const int* __restrict__ mode, int n2) {
  const int i = blockIdx.x * 256 + threadIdx.x;
  if (i >= n2) return;
  if (*mode) { const u32 u = ((const u32*)xin)[i]; out[i] = make_float2(lo16(u), hi16(u)); }
  else out[i] = ((const float2*)xin)[i];
}

// fp32 residual -> fp32 output (straight copy, float4 vectorized)
__global__ void k_out(const float4* __restrict__ in, float4* __restrict__ out, int n4) {
  const int i = blockIdx.x * 256 + threadIdx.x;
  if (i < n4) out[i] = in[i];
}

// dst[Cn][R] = src[eoff + r*Cn0 + c]^T -> bf16. Cn0 = source row stride (elements).
__global__ void k_transpose(const void* __restrict__ src, bf16* __restrict__ dst,
                            const int* __restrict__ mode, int eoff, int R, int Cn, int Cn0) {
  const int i = blockIdx.x * 256 + threadIdx.x;
  const int r = i % R, c = i / R;
  if (c >= Cn) return;
  ((u16*)dst)[i] = f2b(in_elem(src, (size_t)eoff + (size_t)r * Cn0 + c, *mode));
}

// ---------------- LayerNorm (+ optional shift + window partition) ----------------
__global__ __launch_bounds__(256) void k_ln(const float* __restrict__ xf,
    const void* __restrict__ gamw, const void* __restrict__ betw,
    bf16* __restrict__ outp, const int* __restrict__ mode, int eoff,
    int windowed, int shift)
{
  const int m = *mode;
  const int l = threadIdx.x & 63, w = threadIdx.x >> 6;
  const int row = blockIdx.x * 4 + w;
  int srow;
  if (windowed) {
    const int t = row & 63, win = row >> 6;
    const int bb = win >> 6, wi = win & 63;
    const int gh = ((wi >> 3) << 3) + (t >> 3);
    const int gw = ((wi & 7) << 3) + (t & 7);
    const int sh = (gh + shift) & 63, sw = (gw + shift) & 63;
    srow = (bb << 12) + (sh << 6) + sw;
  } else {
    srow = row;
  }
  const float4 v = ((const float4*)(xf + (size_t)srow * 256))[l];
  float s = v.x + v.y + v.z + v.w;
#pragma unroll
  for (int off = 32; off > 0; off >>= 1) s += __shfl_xor(s, off, 64);
  const float mu = s * 0.00390625f;
  const float a = v.x - mu, b = v.y - mu, c = v.z - mu, d = v.w - mu;
  float q = a * a + b * b + c * c + d * d;
#pragma unroll
  for (int off = 32; off > 0; off >>= 1) q += __shfl_xor(q, off, 64);
  const float rs = rsqrtf(q * 0.00390625f + 1e-5f);
  const int cb = l << 2;
  const float o0 = a * rs * in_elem(gamw, eoff + cb + 0, m) + in_elem(betw, eoff + cb + 0, m);
  const float o1 = b * rs * in_elem(gamw, eoff + cb + 1, m) + in_elem(betw, eoff + cb + 1, m);
  const float o2 = c * rs * in_elem(gamw, eoff + cb + 2, m) + in_elem(betw, eoff + cb + 2, m);
  const float o3 = d * rs * in_elem(gamw, eoff + cb + 3, m) + in_elem(betw, eoff + cb + 3, m);
  const u32 p0 = (u32)f2b(o0) | ((u32)f2b(o1) << 16);
  const u32 p1 = (u32)f2b(o2) | ((u32)f2b(o3) << 16);
  *(uint2*)((u16*)outp + (size_t)row * 256 + cb) = make_uint2(p0, p1);
}

// ---------------- bf16 MFMA GEMM: C[M,N] = A[M,K] @ Bt[N,K]^T + bmul*bias ----------------
// 128x128 tile, 4 waves (2x2 of 64x64), 16x16x32 bf16 MFMA, register-mediated staging.
// EPI: 0 = store bf16; 1 = GELU(exact)+store; 2 = window-reverse(+shift)+fp32 residual;
//      3 = fp32 residual add (identity rows).
template <int EPI>
__global__ __launch_bounds__(256, 2) void k_gemm(
    const bf16* __restrict__ A, const bf16* __restrict__ Bt,
    const void* __restrict__ bias, bf16* __restrict__ outb,
    float* __restrict__ outf, const int* __restrict__ mode,
    int boff, int bmul, int K, int N, int shift)
{
  __shared__ __align__(16) bf16 As[128 * 32];
  __shared__ __align__(16) bf16 Bs[128 * 32];
  const int md = *mode;
  const int tid = threadIdx.x;
  const int l = tid & 63, wid = tid >> 6;
  const int wr = wid >> 1, wc = wid & 1;
  const int row0 = blockIdx.y * 128;
  const int col0 = blockIdx.x * 128;
  const int lrow = l >> 2;
  const int lkof = (l & 3) * 8;

  floatx4 acc[4][4];
#pragma unroll
  for (int mi = 0; mi < 4; ++mi)
#pragma unroll
    for (int ni = 0; ni < 4; ++ni)
      acc[mi][ni] = (floatx4){0.f, 0.f, 0.f, 0.f};

  const bf16* Abase = A + (size_t)(row0 + wid * 16 + lrow) * K + lkof;
  const bf16* Bbase = Bt + (size_t)(col0 + wid * 16 + lrow) * K + lkof;
  const size_t seg_stride = (size_t)64 * K;

  for (int k0 = 0; k0 < K; k0 += 32) {
    const uint4 a0 = *(const uint4*)(Abase + k0);
    const uint4 a1 = *(const uint4*)(Abase + seg_stride + k0);
    const uint4 b0 = *(const uint4*)(Bbase + k0);
    const uint4 b1 = *(const uint4*)(Bbase + seg_stride + k0);
    __syncthreads();
    *(uint4*)&As[wid * 512 + l * 8] = a0;
    *(uint4*)&As[(wid + 4) * 512 + l * 8] = a1;
    *(uint4*)&Bs[wid * 512 + l * 8] = b0;
    *(uint4*)&Bs[(wid + 4) * 512 + l * 8] = b1;
    __syncthreads();

    short8 af[4], bf8[4];
#pragma unroll
    for (int mi = 0; mi < 4; ++mi)
      af[mi] = *(const short8*)&As[(wr * 64 + mi * 16 + (l & 15)) * 32 + (l >> 4) * 8];
#pragma unroll
    for (int ni = 0; ni < 4; ++ni)
      bf8[ni] = *(const short8*)&Bs[(wc * 64 + ni * 16 + (l & 15)) * 32 + (l >> 4) * 8];
#pragma unroll
    for (int mi = 0; mi < 4; ++mi)
#pragma unroll
      for (int ni = 0; ni < 4; ++ni)
        acc[mi][ni] = __builtin_amdgcn_mfma_f32_16x16x32_bf16(af[mi], bf8[ni], acc[mi][ni], 0, 0, 0);
  }

  const int cl = l & 15, rq = l >> 4;  // C/D: col=lane&15, row=(lane>>4)*4+reg
#pragma unroll
  for (int mi = 0; mi < 4; ++mi) {
#pragma unroll
    for (int ni = 0; ni < 4; ++ni) {
      const int col = col0 + wc * 64 + ni * 16 + cl;
      const float bv = in_elem(bias, (size_t)boff + col, md) * (float)bmul;
#pragma unroll
      for (int r = 0; r < 4; ++r) {
        const int row = row0 + wr * 64 + mi * 16 + rq * 4 + r;
        float v = acc[mi][ni][r] + bv;
        if (EPI == 0) {
          ((u16*)outb)[(size_t)row * N + col] = f2b(v);
        } else if (EPI == 1) {
          v = 0.5f * v * (1.f + erff(v * 0.70710678118654752440f));
          ((u16*)outb)[(size_t)row * N + col] = f2b(v);
        } else if (EPI == 2) {
          const int t = row & 63, win = row >> 6;
          const int bb = win >> 6, wi = win & 63;
          int gh = ((wi >> 3) << 3) + (t >> 3);
          int gw = ((wi & 7) << 3) + (t & 7);
          gh = (gh + shift) & 63; gw = (gw + shift) & 63;
          outf[(((size_t)bb << 12) + (gh << 6) + gw) * 256 + col] += v;
        } else {
          outf[(size_t)row * 256 + col] += v;
        }
      }
    }
  }
}

// ---------------- windowed attention (VALU; lane = query token) ----------------
__global__ __launch_bounds__(256, 2) void k_attn(
    const bf16* __restrict__ qkv, const void* __restrict__ rpb,
    bf16* __restrict__ outp, const int* __restrict__ mode, int eoff, int shifted)
{
  __shared__ u32 KV[4][2][64][16];   // 32 KB
  __shared__ float rpbs[4][228];
  const int md = *mode;
  const int l = threadIdx.x & 63, w = threadIdx.x >> 6;
  const int win = blockIdx.x;
  const int wi = win & 63;
  const int whb = (wi >> 3) << 3, wwb = (wi & 7) << 3;
  const int ty = l >> 3, tx = l & 7;
  const bf16* rowp = qkv + ((size_t)win * 64 + l) * 768;
  int myl = 0;
  if (shifted) {
    const int gh = whb + ty, gw = wwb + tx;
    myl = ((gh < 56) ? 0 : (gh < 60 ? 1 : 2)) * 3 + ((gw < 56) ? 0 : (gw < 60 ? 1 : 2));
  }
  for (int hh = 0; hh < 2; ++hh) {
    const int h = w + hh * 4;
    float q[32];
    {
      const uint4* q4 = (const uint4*)(rowp + h * 32);
      const uint4* k4 = (const uint4*)(rowp + 256 + h * 32);
      const uint4* v4 = (const uint4*)(rowp + 512 + h * 32);
#pragma unroll
      for (int i = 0; i < 4; ++i) {
        const uint4 u = q4[i];
        q[i*8+0]=lo16(u.x); q[i*8+1]=hi16(u.x); q[i*8+2]=lo16(u.y); q[i*8+3]=hi16(u.y);
        q[i*8+4]=lo16(u.z); q[i*8+5]=hi16(u.z); q[i*8+6]=lo16(u.w); q[i*8+7]=hi16(u.w);
        *(uint4*)&KV[w][0][l][i*4] = k4[i];
        *(uint4*)&KV[w][1][l][i*4] = v4[i];
      }
    }
#pragma unroll
    for (int d = 0; d < 32; ++d) q[d] *= 0.17677669529663687f;
    for (int i = l; i < 225; i += 64)
      rpbs[w][i] = in_elem(rpb, (size_t)eoff + (size_t)i * 8 + h, md);
    __syncthreads();

    float s[64];
    float mx = -3.0e38f;
#pragma unroll
    for (int m = 0; m < 64; ++m) {
      float acc = 0.f;
#pragma unroll
      for (int i = 0; i < 16; ++i) {
        const u32 u = KV[w][0][m][i];
        acc += q[2*i] * lo16(u);
        acc += q[2*i+1] * hi16(u);
      }
      const int my = m >> 3, mxp = m & 7;
      acc += rpbs[w][(ty - my + 7) * 15 + (tx - mxp + 7)];
      if (shifted) {
        const int gh = whb + my, gw = wwb + mxp;
        const int ml = ((gh < 56) ? 0 : (gh < 60 ? 1 : 2)) * 3 + ((gw < 56) ? 0 : (gw < 60 ? 1 : 2));
        if (ml != myl) acc -= 100.f;
      }
      s[m] = acc;
      mx = fmaxf(mx, acc);
    }
    float sum = 0.f;
#pragma unroll
    for (int m = 0; m < 64; ++m) { s[m] = __expf(s[m] - mx); sum += s[m]; }
    const float inv = 1.f / sum;
    float o[32];
#pragma unroll
    for (int d = 0; d < 32; ++d) o[d] = 0.f;
#pragma unroll
    for (int m = 0; m < 64; ++m) {
      const float p = s[m];
#pragma unroll
      for (int i = 0; i < 16; ++i) {
        const u32 u = KV[w][1][m][i];
        o[2*i]   += p * lo16(u);
        o[2*i+1] += p * hi16(u);
      }
    }
    u32 ou[16];
#pragma unroll
    for (int i = 0; i < 16; ++i)
      ou[i] = (u32)f2b(o[2*i] * inv) | ((u32)f2b(o[2*i+1] * inv) << 16);
    uint4* op = (uint4*)((u16*)outp + ((size_t)win * 64 + l) * 256 + h * 32);
#pragma unroll
    for (int i = 0; i < 4; ++i) op[i] = *(const uint4*)&ou[i*4];
    __syncthreads();
  }
}

// ---------------- host launcher ----------------
extern "C" void kernel_launch(void* const* d_in, const int* in_sizes, int n_in,
                              void* d_out, int out_size, void* d_ws, size_t ws_size,
                              hipStream_t stream) {
  (void)in_sizes; (void)n_in; (void)out_size; (void)ws_size;
  const void* x_in   = d_in[0];
  const void* qkv_w  = d_in[1];
  const void* qkv_b  = d_in[2];
  const void* proj_w = d_in[3];
  const void* proj_b = d_in[4];
  const void* ln1_g  = d_in[5];
  const void* ln1_b  = d_in[6];
  const void* ln2_g  = d_in[7];
  const void* ln2_b  = d_in[8];
  const void* fc1_w  = d_in[9];
  const void* fc1_b  = d_in[10];
  const void* fc2_w  = d_in[11];
  const void* fc2_b  = d_in[12];
  const void* rpb    = d_in[13];

  char* ws = (char*)d_ws;
  float* xf  = (float*)ws;                   // 32 MiB
  bf16* bufQ = (bf16*)(ws + 33554432);       // 48 MiB: qkv, later fc1 hidden halves
  bf16* bufB = (bf16*)(ws + 83886080);       // 16 MiB: LN out / attn out
  bf16* wT   = (bf16*)(ws + 100663296);      // 3 MiB
  int* mode  = (int*)(ws + 103809024);       // 4 B

  k_detect<<<1, 1, 0, stream>>>((const u32*)ln1_g, mode);
  k_ingest<<<16384, 256, 0, stream>>>(x_in, (float2*)xf, mode, 4194304);

  // per-depth transposed weights: qkvT[768][256], projT[256][256], fc1T[1024][256],
  // fc2Tc0[256][512] (K rows 0..511), fc2Tc1[256][512] (K rows 512..1023)
  for (int i = 0; i < 2; ++i) {
    bf16* base = wT + (size_t)i * 786432;
    k_transpose<<<768, 256, 0, stream>>>(qkv_w,  base,          mode, i * 196608, 256, 768, 768);
    k_transpose<<<256, 256, 0, stream>>>(proj_w, base + 196608, mode, i * 65536, 256, 256, 256);
    k_transpose<<<1024, 256, 0, stream>>>(fc1_w, base + 262144, mode, i * 262144, 256, 1024, 1024);
    k_transpose<<<512, 256, 0, stream>>>(fc2_w,  base + 524288, mode, i * 262144,          512, 256, 256);
    k_transpose<<<512, 256, 0, stream>>>(fc2_w,  base + 655360, mode, i * 262144 + 131072, 512, 256, 256);
  }

  for (int i = 0; i < 2; ++i) {
    const int shift = i ? 4 : 0;
    bf16* base  = wT + (size_t)i * 786432;
    bf16* qkvT  = base;
    bf16* projT = base + 196608;
    bf16* fc1T  = base + 262144;

    // LN1 + (shift) + window partition -> bufB
    k_ln<<<8192, 256, 0, stream>>>(xf, ln1_g, ln1_b, bufB, mode, i * 256, 1, shift);
    // QKV: bufQ[32768,768] = bufB @ qkv_w + b
    k_gemm<0><<<dim3(6, 256), 256, 0, stream>>>(bufB, qkvT, qkv_b, bufQ, nullptr, mode, i * 768, 1, 256, 768, 0);
    // windowed attention: bufQ -> bufB (LN1-out dead after qkv GEMM)
    k_attn<<<512, 256, 0, stream>>>(bufQ, rpb, bufB, mode, i * 1800, i);
    // proj + window-reverse + unshift + residual add into xf
    k_gemm<2><<<dim3(2, 256), 256, 0, stream>>>(bufB, projT, proj_b, nullptr, xf, mode, i * 256, 1, 256, 256, shift);
    // LN2 -> bufB
    k_ln<<<8192, 256, 0, stream>>>(xf, ln2_g, ln2_b, bufB, mode, i * 256, 0, 0);
    // MLP in two hidden-half chunks (hidden buffer = bufQ base, 32 MiB)
    for (int c = 0; c < 2; ++c) {
      bf16* fc2Tc = base + 524288 + c * 131072;
      // FC1 half: bufQ[32768,512] = GELU(bufB @ fc1_w[:, c*512:+512] + b)
      k_gemm<1><<<dim3(4, 256), 256, 0, stream>>>(bufB, fc1T + (size_t)c * 131072, fc1_b, bufQ, nullptr,
                                                  mode, i * 1024 + c * 512, 1, 256, 512, 0);
      // FC2 partial (K=512) + residual add into xf; bias only on chunk 0
      k_gemm<3><<<dim3(2, 256), 256, 0, stream>>>(bufQ, fc2Tc, fc2_b, nullptr, xf,
                                                  mode, i * 256, c == 0 ? 1 : 0, 512, 256, 0);
    }
  }

  // fp32 residual -> fp32 output
  k_out<<<8192, 256, 0, stream>>>((const float4*)xf, (float4*)d_out, 2097152);
}

// Round 6
// 600.122 us; speedup vs baseline: 1.2672x; 1.2672x over previous
//
#include <hip/hip_runtime.h>
#include <hip/hip_bf16.h>

// SwinTransformerEncoder on gfx950.
// H=W=64, C=256, HEADS=8 (d=32), WS=8, N=64 tok/window, NW=64, B=8, DEPTH=2, HIDDEN=1024.
// Inputs fp32 (runtime probe also supports bf16-cast). OUTPUT fp32. Residual fp32 in ws.
// R6: (1) MFMA attention (was VALU w/ s[64] scratch spill: WRITE_SIZE 71MB vs 16MB out);
//     (2) k_gemm staging via global_load_lds width=16 (m97 pattern; rounds 1-2 NaN was
//         the input-dtype bug, not this path).
//
// Workspace (99.0 MiB total):
//   xf   fp32 [8*4096*256]   @ 0          (32 MiB)  residual stream
//   bufQ bf16 [32768*768]    @ 33554432   (48 MiB)  qkv; later fc1 hidden halves [32768*512]
//   bufB bf16 [32768*256]    @ 83886080   (16 MiB)  LN out, then attn out
//   wT   bf16 [2*786432]     @ 100663296  (3 MiB)   transposed weights
//   mode int                 @ 103809024  (4 B)     input-dtype flag (1=bf16, 0=fp32)

typedef __hip_bfloat16 bf16;
typedef unsigned short u16;
typedef unsigned int u32;
typedef short short8 __attribute__((ext_vector_type(8)));
typedef float floatx4 __attribute__((ext_vector_type(4)));

#define DEVI static __device__ __forceinline__

DEVI float lo16(u32 u) { union { u32 i; float f; } x; x.i = u << 16; return x.f; }
DEVI float hi16(u32 u) { union { u32 i; float f; } x; x.i = u & 0xffff0000u; return x.f; }
DEVI float b2f(u16 u) { union { u32 i; float f; } x; x.i = ((u32)u) << 16; return x.f; }
DEVI u16 f2b(float f) {  // round-to-nearest-even
  union { float f; u32 i; } x; x.f = f;
  u32 r = x.i + 0x7fffu + ((x.i >> 16) & 1u);
  return (u16)(r >> 16);
}
DEVI float in_elem(const void* p, size_t i, int m) {
  return m ? b2f(((const u16*)p)[i]) : ((const float*)p)[i];
}
DEVI int swlab(int g) { return (g < 56) ? 0 : (g < 60 ? 1 : 2); }

DEVI void async16(const bf16* g, bf16* l) {
  // global -> LDS direct, 16 B per lane; LDS dest = wave-uniform base + lane*16
  __builtin_amdgcn_global_load_lds((const __attribute__((address_space(1))) u32*)g,
                                   (__attribute__((address_space(3))) u32*)l, 16, 0, 0);
}

// ---------------- dtype probe (ln1_g is all-ones) ----------------
__global__ void k_detect(const u32* __restrict__ ln1g, int* __restrict__ mode) {
  if (threadIdx.x == 0 && blockIdx.x == 0)
    *mode = (ln1g[0] == 0x3F803F80u) ? 1 : 0;
}

// ---------------- ingest x -> fp32 residual ----------------
__global__ void k_ingest(const void* __restrict__ xin, float2* __restrict__ out,
                         const int* __restrict__ mode, int n2) {
  const int i = blockIdx.x * 256 + threadIdx.x;
  if (i >= n2) return;
  if (*mode) { const u32 u = ((const u32*)xin)[i]; out[i] = make_float2(lo16(u), hi16(u)); }
  else out[i] = ((const float2*)xin)[i];
}

// fp32 residual -> fp32 output
__global__ void k_out(const float4* __restrict__ in, float4* __restrict__ out, int n4) {
  const int i = blockIdx.x * 256 + threadIdx.x;
  if (i < n4) out[i] = in[i];
}

// dst[Cn][R] = src[eoff + r*Cn0 + c]^T -> bf16. Cn0 = source row stride (elements).
__global__ void k_transpose(const void* __restrict__ src, bf16* __restrict__ dst,
                            const int* __restrict__ mode, int eoff, int R, int Cn, int Cn0) {
  const int i = blockIdx.x * 256 + threadIdx.x;
  const int r = i % R, c = i / R;
  if (c >= Cn) return;
  ((u16*)dst)[i] = f2b(in_elem(src, (size_t)eoff + (size_t)r * Cn0 + c, *mode));
}

// ---------------- LayerNorm (+ optional shift + window partition) ----------------
__global__ __launch_bounds__(256) void k_ln(const float* __restrict__ xf,
    const void* __restrict__ gamw, const void* __restrict__ betw,
    bf16* __restrict__ outp, const int* __restrict__ mode, int eoff,
    int windowed, int shift)
{
  const int m = *mode;
  const int l = threadIdx.x & 63, w = threadIdx.x >> 6;
  const int row = blockIdx.x * 4 + w;
  int srow;
  if (windowed) {
    const int t = row & 63, win = row >> 6;
    const int bb = win >> 6, wi = win & 63;
    const int gh = ((wi >> 3) << 3) + (t >> 3);
    const int gw = ((wi & 7) << 3) + (t & 7);
    const int sh = (gh + shift) & 63, sw = (gw + shift) & 63;
    srow = (bb << 12) + (sh << 6) + sw;
  } else {
    srow = row;
  }
  const float4 v = ((const float4*)(xf + (size_t)srow * 256))[l];
  float s = v.x + v.y + v.z + v.w;
#pragma unroll
  for (int off = 32; off > 0; off >>= 1) s += __shfl_xor(s, off, 64);
  const float mu = s * 0.00390625f;
  const float a = v.x - mu, b = v.y - mu, c = v.z - mu, d = v.w - mu;
  float q = a * a + b * b + c * c + d * d;
#pragma unroll
  for (int off = 32; off > 0; off >>= 1) q += __shfl_xor(q, off, 64);
  const float rs = rsqrtf(q * 0.00390625f + 1e-5f);
  const int cb = l << 2;
  const float o0 = a * rs * in_elem(gamw, eoff + cb + 0, m) + in_elem(betw, eoff + cb + 0, m);
  const float o1 = b * rs * in_elem(gamw, eoff + cb + 1, m) + in_elem(betw, eoff + cb + 1, m);
  const float o2 = c * rs * in_elem(gamw, eoff + cb + 2, m) + in_elem(betw, eoff + cb + 2, m);
  const float o3 = d * rs * in_elem(gamw, eoff + cb + 3, m) + in_elem(betw, eoff + cb + 3, m);
  const u32 p0 = (u32)f2b(o0) | ((u32)f2b(o1) << 16);
  const u32 p1 = (u32)f2b(o2) | ((u32)f2b(o3) << 16);
  *(uint2*)((u16*)outp + (size_t)row * 256 + cb) = make_uint2(p0, p1);
}

// ---------------- bf16 MFMA GEMM: C[M,N] = A[M,K] @ Bt[N,K]^T + bmul*bias ----------------
// 128x128 tile, 4 waves (2x2 of 64x64), 16x16x32 bf16 MFMA, global_load_lds w=16 staging.
// EPI: 0 = store bf16; 1 = GELU(exact)+store; 2 = window-reverse(+shift)+fp32 residual;
//      3 = fp32 residual add (identity rows).
template <int EPI>
__global__ __launch_bounds__(256, 2) void k_gemm(
    const bf16* __restrict__ A, const bf16* __restrict__ Bt,
    const void* __restrict__ bias, bf16* __restrict__ outb,
    float* __restrict__ outf, const int* __restrict__ mode,
    int boff, int bmul, int K, int N, int shift)
{
  __shared__ __align__(16) bf16 As[128 * 32];
  __shared__ __align__(16) bf16 Bs[128 * 32];
  const int md = *mode;
  const int tid = threadIdx.x;
  const int l = tid & 63, wid = tid >> 6;
  const int wr = wid >> 1, wc = wid & 1;
  const int row0 = blockIdx.y * 128;
  const int col0 = blockIdx.x * 128;
  const int lrow = l >> 2;          // row within 16-row segment
  const int lkof = (l & 3) * 8;     // k-offset (8 bf16 = 16 B)

  floatx4 acc[4][4];
#pragma unroll
  for (int mi = 0; mi < 4; ++mi)
#pragma unroll
    for (int ni = 0; ni < 4; ++ni)
      acc[mi][ni] = (floatx4){0.f, 0.f, 0.f, 0.f};

  for (int k0 = 0; k0 < K; k0 += 32) {
    __syncthreads();  // all waves done reading previous LDS tiles
#pragma unroll
    for (int c = 0; c < 2; ++c) {
      const int seg = c * 4 + wid;  // 8 segments of 16 rows each
      async16(A + (size_t)(row0 + seg * 16 + lrow) * K + (k0 + lkof), &As[seg * 512]);
      async16(Bt + (size_t)(col0 + seg * 16 + lrow) * K + (k0 + lkof), &Bs[seg * 512]);
    }
    __syncthreads();  // vmcnt(0) drain before barrier -> staging complete

    short8 af[4], bf8[4];
#pragma unroll
    for (int mi = 0; mi < 4; ++mi)
      af[mi] = *(const short8*)&As[(wr * 64 + mi * 16 + (l & 15)) * 32 + (l >> 4) * 8];
#pragma unroll
    for (int ni = 0; ni < 4; ++ni)
      bf8[ni] = *(const short8*)&Bs[(wc * 64 + ni * 16 + (l & 15)) * 32 + (l >> 4) * 8];
#pragma unroll
    for (int mi = 0; mi < 4; ++mi)
#pragma unroll
      for (int ni = 0; ni < 4; ++ni)
        acc[mi][ni] = __builtin_amdgcn_mfma_f32_16x16x32_bf16(af[mi], bf8[ni], acc[mi][ni], 0, 0, 0);
  }

  const int cl = l & 15, rq = l >> 4;  // C/D: col=lane&15, row=(lane>>4)*4+reg
#pragma unroll
  for (int mi = 0; mi < 4; ++mi) {
#pragma unroll
    for (int ni = 0; ni < 4; ++ni) {
      const int col = col0 + wc * 64 + ni * 16 + cl;
      const float bv = in_elem(bias, (size_t)boff + col, md) * (float)bmul;
#pragma unroll
      for (int r = 0; r < 4; ++r) {
        const int row = row0 + wr * 64 + mi * 16 + rq * 4 + r;
        float v = acc[mi][ni][r] + bv;
        if (EPI == 0) {
          ((u16*)outb)[(size_t)row * N + col] = f2b(v);
        } else if (EPI == 1) {
          v = 0.5f * v * (1.f + erff(v * 0.70710678118654752440f));
          ((u16*)outb)[(size_t)row * N + col] = f2b(v);
        } else if (EPI == 2) {
          const int t = row & 63, win = row >> 6;
          const int bb = win >> 6, wi = win & 63;
          int gh = ((wi >> 3) << 3) + (t >> 3);
          int gw = ((wi & 7) << 3) + (t & 7);
          gh = (gh + shift) & 63; gw = (gw + shift) & 63;
          outf[(((size_t)bb << 12) + (gh << 6) + gw) * 256 + col] += v;
        } else {
          outf[(size_t)row * 256 + col] += v;
        }
      }
    }
  }
}

// ---------------- windowed attention (MFMA; wave = window x head, 2 heads/wave) ----------------
// S[64,64] = Q[64,32] K^T via 16 mfma_16x16x32 (A/B frags 16B-contiguous direct from qkv).
// Softmax in C-layout regs (shfl_xor over the 16 lanes holding each row).
// P -> LDS (bf16, stride 72) -> A-layout frags; V^T staged in LDS (stride 72) for B frags.
// O = P V via 16 mfma; normalize by row-sum in epilogue.
__global__ __launch_bounds__(256, 2) void k_attn(
    const bf16* __restrict__ qkv, const void* __restrict__ rpb,
    bf16* __restrict__ outp, const int* __restrict__ mode, int eoff, int shifted)
{
  __shared__ __align__(16) u16 Pl[4][64][72];   // 36864 B
  __shared__ __align__(16) u16 Vt[4][32][72];   // 18432 B
  __shared__ float rpbs[4][228];                //  3648 B
  const int md = *mode;
  const int l = threadIdx.x & 63, w = threadIdx.x >> 6;
  const int cl = l & 15, qd = l >> 4;
  const int ko = qd * 8;
  const int win = blockIdx.x;
  const int wi = win & 63;
  const int whb = (wi >> 3) << 3, wwb = (wi & 7) << 3;
  const size_t rowbase = (size_t)win * 64 * 768;

  for (int hh = 0; hh < 2; ++hh) {
    const int h = w + hh * 4;
    // stage rel-pos bias table for this head (per-wave)
    for (int i = l; i < 225; i += 64)
      rpbs[w][i] = in_elem(rpb, (size_t)eoff + (size_t)i * 8 + h, md);
    // stage V^T: lane = token, Vt[dim][token]
    {
      const u16* vrow = (const u16*)(qkv + rowbase + (size_t)l * 768 + 512 + h * 32);
#pragma unroll
      for (int n = 0; n < 32; ++n) Vt[w][n][l] = vrow[n];
    }
    // load Q,K fragments (A/B layout: lane holds [m|n = cl][k = ko..ko+8))
    short8 qf[4], kf[4];
#pragma unroll
    for (int t = 0; t < 4; ++t) {
      qf[t] = *(const short8*)(qkv + rowbase + (size_t)(t * 16 + cl) * 768 + h * 32 + ko);
      kf[t] = *(const short8*)(qkv + rowbase + (size_t)(t * 16 + cl) * 768 + 256 + h * 32 + ko);
    }
    __syncthreads();  // rpbs + Vt visible (also guards prev-iter LDS reads)

    // S = Q K^T
    floatx4 S[4][4];
#pragma unroll
    for (int mi = 0; mi < 4; ++mi)
#pragma unroll
      for (int ni = 0; ni < 4; ++ni)
        S[mi][ni] = __builtin_amdgcn_mfma_f32_16x16x32_bf16(qf[mi], kf[ni], (floatx4){0.f, 0.f, 0.f, 0.f}, 0, 0, 0);

    // column-token metadata for this lane
    int cty[4], ctx[4], clab[4];
#pragma unroll
    for (int ni = 0; ni < 4; ++ni) {
      const int ct = ni * 16 + cl;
      cty[ni] = ct >> 3; ctx[ni] = ct & 7;
      clab[ni] = shifted ? (swlab(whb + cty[ni]) * 3 + swlab(wwb + ctx[ni])) : 0;
    }

    // scale + bias + mask + row softmax; write P (un-normalized exp) to LDS
    float invs[4][4];
#pragma unroll
    for (int mi = 0; mi < 4; ++mi) {
#pragma unroll
      for (int r = 0; r < 4; ++r) {
        const int rt = mi * 16 + qd * 4 + r;
        const int rty = rt >> 3, rtx = rt & 7;
        const int rlab = shifted ? (swlab(whb + rty) * 3 + swlab(wwb + rtx)) : 0;
        float sv[4];
#pragma unroll
        for (int ni = 0; ni < 4; ++ni) {
          float x = S[mi][ni][r] * 0.17677669529663687f;
          x += rpbs[w][(rty - cty[ni] + 7) * 15 + (rtx - ctx[ni] + 7)];
          if (shifted && (rlab != clab[ni])) x -= 100.f;
          sv[ni] = x;
        }
        float mx = fmaxf(fmaxf(sv[0], sv[1]), fmaxf(sv[2], sv[3]));
        mx = fmaxf(mx, __shfl_xor(mx, 1, 64));
        mx = fmaxf(mx, __shfl_xor(mx, 2, 64));
        mx = fmaxf(mx, __shfl_xor(mx, 4, 64));
        mx = fmaxf(mx, __shfl_xor(mx, 8, 64));
        float sum = 0.f;
#pragma unroll
        for (int ni = 0; ni < 4; ++ni) { sv[ni] = __expf(sv[ni] - mx); sum += sv[ni]; }
        sum += __shfl_xor(sum, 1, 64);
        sum += __shfl_xor(sum, 2, 64);
        sum += __shfl_xor(sum, 4, 64);
        sum += __shfl_xor(sum, 8, 64);
        invs[mi][r] = 1.f / sum;
#pragma unroll
        for (int ni = 0; ni < 4; ++ni) Pl[w][rt][ni * 16 + cl] = f2b(sv[ni]);
      }
    }
    __syncthreads();  // P visible

    // O = P V  (A frags from Pl, B frags from Vt)
    floatx4 O[4][2];
#pragma unroll
    for (int mi = 0; mi < 4; ++mi)
#pragma unroll
      for (int nv = 0; nv < 2; ++nv)
        O[mi][nv] = (floatx4){0.f, 0.f, 0.f, 0.f};
    short8 vf[2][2];
#pragma unroll
    for (int nv = 0; nv < 2; ++nv)
#pragma unroll
      for (int kk = 0; kk < 2; ++kk)
        vf[nv][kk] = *(const short8*)&Vt[w][nv * 16 + cl][kk * 32 + ko];
#pragma unroll
    for (int mi = 0; mi < 4; ++mi) {
      const short8 pf0 = *(const short8*)&Pl[w][mi * 16 + cl][ko];
      const short8 pf1 = *(const short8*)&Pl[w][mi * 16 + cl][32 + ko];
#pragma unroll
      for (int nv = 0; nv < 2; ++nv) {
        O[mi][nv] = __builtin_amdgcn_mfma_f32_16x16x32_bf16(pf0, vf[nv][0], O[mi][nv], 0, 0, 0);
        O[mi][nv] = __builtin_amdgcn_mfma_f32_16x16x32_bf16(pf1, vf[nv][1], O[mi][nv], 0, 0, 0);
      }
    }

    // normalize + store (C layout: row = mi*16 + qd*4 + r, col = nv*16 + cl)
#pragma unroll
    for (int mi = 0; mi < 4; ++mi)
#pragma unroll
      for (int nv = 0; nv < 2; ++nv)
#pragma unroll
        for (int r = 0; r < 4; ++r) {
          const int row = mi * 16 + qd * 4 + r;
          ((u16*)outp)[((size_t)win * 64 + row) * 256 + h * 32 + nv * 16 + cl] =
              f2b(O[mi][nv][r] * invs[mi][r]);
        }
    __syncthreads();  // guard Pl/Vt/rpbs overwrite next iteration
  }
}

// ---------------- host launcher ----------------
extern "C" void kernel_launch(void* const* d_in, const int* in_sizes, int n_in,
                              void* d_out, int out_size, void* d_ws, size_t ws_size,
                              hipStream_t stream) {
  (void)in_sizes; (void)n_in; (void)out_size; (void)ws_size;
  const void* x_in   = d_in[0];
  const void* qkv_w  = d_in[1];
  const void* qkv_b  = d_in[2];
  const void* proj_w = d_in[3];
  const void* proj_b = d_in[4];
  const void* ln1_g  = d_in[5];
  const void* ln1_b  = d_in[6];
  const void* ln2_g  = d_in[7];
  const void* ln2_b  = d_in[8];
  const void* fc1_w  = d_in[9];
  const void* fc1_b  = d_in[10];
  const void* fc2_w  = d_in[11];
  const void* fc2_b  = d_in[12];
  const void* rpb    = d_in[13];

  char* ws = (char*)d_ws;
  float* xf  = (float*)ws;                   // 32 MiB
  bf16* bufQ = (bf16*)(ws + 33554432);       // 48 MiB: qkv, later fc1 hidden halves
  bf16* bufB = (bf16*)(ws + 83886080);       // 16 MiB: LN out / attn out
  bf16* wT   = (bf16*)(ws + 100663296);      // 3 MiB
  int* mode  = (int*)(ws + 103809024);       // 4 B

  k_detect<<<1, 1, 0, stream>>>((const u32*)ln1_g, mode);
  k_ingest<<<16384, 256, 0, stream>>>(x_in, (float2*)xf, mode, 4194304);

  // per-depth transposed weights: qkvT[768][256], projT[256][256], fc1T[1024][256],
  // fc2Tc0[256][512] (K rows 0..511), fc2Tc1[256][512] (K rows 512..1023)
  for (int i = 0; i < 2; ++i) {
    bf16* base = wT + (size_t)i * 786432;
    k_transpose<<<768, 256, 0, stream>>>(qkv_w,  base,          mode, i * 196608, 256, 768, 768);
    k_transpose<<<256, 256, 0, stream>>>(proj_w, base + 196608, mode, i * 65536, 256, 256, 256);
    k_transpose<<<1024, 256, 0, stream>>>(fc1_w, base + 262144, mode, i * 262144, 256, 1024, 1024);
    k_transpose<<<512, 256, 0, stream>>>(fc2_w,  base + 524288, mode, i * 262144,          512, 256, 256);
    k_transpose<<<512, 256, 0, stream>>>(fc2_w,  base + 655360, mode, i * 262144 + 131072, 512, 256, 256);
  }

  for (int i = 0; i < 2; ++i) {
    const int shift = i ? 4 : 0;
    bf16* base  = wT + (size_t)i * 786432;
    bf16* qkvT  = base;
    bf16* projT = base + 196608;
    bf16* fc1T  = base + 262144;

    // LN1 + (shift) + window partition -> bufB
    k_ln<<<8192, 256, 0, stream>>>(xf, ln1_g, ln1_b, bufB, mode, i * 256, 1, shift);
    // QKV: bufQ[32768,768] = bufB @ qkv_w + b
    k_gemm<0><<<dim3(6, 256), 256, 0, stream>>>(bufB, qkvT, qkv_b, bufQ, nullptr, mode, i * 768, 1, 256, 768, 0);
    // windowed attention: bufQ -> bufB
    k_attn<<<512, 256, 0, stream>>>(bufQ, rpb, bufB, mode, i * 1800, i);
    // proj + window-reverse + unshift + residual add into xf
    k_gemm<2><<<dim3(2, 256), 256, 0, stream>>>(bufB, projT, proj_b, nullptr, xf, mode, i * 256, 1, 256, 256, shift);
    // LN2 -> bufB
    k_ln<<<8192, 256, 0, stream>>>(xf, ln2_g, ln2_b, bufB, mode, i * 256, 0, 0);
    // MLP in two hidden-half chunks (hidden buffer = bufQ base, 32 MiB)
    for (int c = 0; c < 2; ++c) {
      bf16* fc2Tc = base + 524288 + c * 131072;
      // FC1 half: bufQ[32768,512] = GELU(bufB @ fc1_w[:, c*512:+512] + b)
      k_gemm<1><<<dim3(4, 256), 256, 0, stream>>>(bufB, fc1T + (size_t)c * 131072, fc1_b, bufQ, nullptr,
                                                  mode, i * 1024 + c * 512, 1, 256, 512, 0);
      // FC2 partial (K=512) + residual add into xf; bias only on chunk 0
      k_gemm<3><<<dim3(2, 256), 256, 0, stream>>>(bufQ, fc2Tc, fc2_b, nullptr, xf,
                                                  mode, i * 256, c == 0 ? 1 : 0, 512, 256, 0);
    }
  }

  // fp32 residual -> fp32 output
  k_out<<<8192, 256, 0, stream>>>((const float4*)xf, (float4*)d_out, 2097152);
}

// Round 7
// 538.578 us; speedup vs baseline: 1.4121x; 1.1143x over previous
//
#include <hip/hip_runtime.h>
#include <hip/hip_bf16.h>

// SwinTransformerEncoder on gfx950.
// H=W=64, C=256, HEADS=8 (d=32), WS=8, N=64 tok/window, NW=64, B=8, DEPTH=2, HIDDEN=1024.
// Inputs fp32 (runtime probe also supports bf16-cast). OUTPUT fp32. Residual fp32 in ws.
// R7: TM=64 GEMM variant for proj/fc2 (occupancy), single-pass MLP (ws is 256 MiB),
//     final-output fusion into fc2 epilogue, transposes batched over depth.
//
// Workspace (~171 MiB of 256 MiB):
//   xf   fp32 [8*4096*256]   @ 0          (32 MiB)  residual stream
//   bufH bf16 [32768*1024]   @ 33554432   (64 MiB)  fc1 hidden
//   bufQ bf16 [32768*768]    @ 100663296  (48 MiB)  qkv
//   bufB bf16 [32768*256]    @ 150994944  (16 MiB)  LN out / attn out
//   wT   bf16 [2*786432]     @ 167772160  (3 MiB)   transposed weights
//   mode int                 @ 170917888  (4 B)     input-dtype flag (1=bf16, 0=fp32)

typedef __hip_bfloat16 bf16;
typedef unsigned short u16;
typedef unsigned int u32;
typedef short short8 __attribute__((ext_vector_type(8)));
typedef float floatx4 __attribute__((ext_vector_type(4)));

#define DEVI static __device__ __forceinline__

DEVI float lo16(u32 u) { union { u32 i; float f; } x; x.i = u << 16; return x.f; }
DEVI float hi16(u32 u) { union { u32 i; float f; } x; x.i = u & 0xffff0000u; return x.f; }
DEVI float b2f(u16 u) { union { u32 i; float f; } x; x.i = ((u32)u) << 16; return x.f; }
DEVI u16 f2b(float f) {  // round-to-nearest-even
  union { float f; u32 i; } x; x.f = f;
  u32 r = x.i + 0x7fffu + ((x.i >> 16) & 1u);
  return (u16)(r >> 16);
}
DEVI float in_elem(const void* p, size_t i, int m) {
  return m ? b2f(((const u16*)p)[i]) : ((const float*)p)[i];
}
DEVI int swlab(int g) { return (g < 56) ? 0 : (g < 60 ? 1 : 2); }

DEVI void async16(const bf16* g, bf16* l) {
  __builtin_amdgcn_global_load_lds((const __attribute__((address_space(1))) u32*)g,
                                   (__attribute__((address_space(3))) u32*)l, 16, 0, 0);
}

// ---------------- dtype probe (ln1_g is all-ones) ----------------
__global__ void k_detect(const u32* __restrict__ ln1g, int* __restrict__ mode) {
  if (threadIdx.x == 0 && blockIdx.x == 0)
    *mode = (ln1g[0] == 0x3F803F80u) ? 1 : 0;
}

// ---------------- ingest x -> fp32 residual ----------------
__global__ void k_ingest(const void* __restrict__ xin, float2* __restrict__ out,
                         const int* __restrict__ mode, int n2) {
  const int i = blockIdx.x * 256 + threadIdx.x;
  if (i >= n2) return;
  if (*mode) { const u32 u = ((const u32*)xin)[i]; out[i] = make_float2(lo16(u), hi16(u)); }
  else out[i] = ((const float2*)xin)[i];
}

// dst[Cn][R] for both depths. src slice d at d*estride, dst slice d at d*dstride.
__global__ void k_transpose(const void* __restrict__ src, bf16* __restrict__ dst,
                            const int* __restrict__ mode, int estride, int dstride,
                            int R, int Cn, int Cn0) {
  const int i = blockIdx.x * 256 + threadIdx.x;
  const int r = i % R, c = i / R;
  if (c >= Cn) return;
  const int m = *mode;
#pragma unroll
  for (int d = 0; d < 2; ++d)
    ((u16*)dst)[(size_t)d * dstride + i] =
        f2b(in_elem(src, (size_t)d * estride + (size_t)r * Cn0 + c, m));
}

// ---------------- LayerNorm (+ optional shift + window partition) ----------------
__global__ __launch_bounds__(256) void k_ln(const float* __restrict__ xf,
    const void* __restrict__ gamw, const void* __restrict__ betw,
    bf16* __restrict__ outp, const int* __restrict__ mode, int eoff,
    int windowed, int shift)
{
  const int m = *mode;
  const int l = threadIdx.x & 63, w = threadIdx.x >> 6;
  const int row = blockIdx.x * 4 + w;
  int srow;
  if (windowed) {
    const int t = row & 63, win = row >> 6;
    const int bb = win >> 6, wi = win & 63;
    const int gh = ((wi >> 3) << 3) + (t >> 3);
    const int gw = ((wi & 7) << 3) + (t & 7);
    const int sh = (gh + shift) & 63, sw = (gw + shift) & 63;
    srow = (bb << 12) + (sh << 6) + sw;
  } else {
    srow = row;
  }
  const float4 v = ((const float4*)(xf + (size_t)srow * 256))[l];
  float s = v.x + v.y + v.z + v.w;
#pragma unroll
  for (int off = 32; off > 0; off >>= 1) s += __shfl_xor(s, off, 64);
  const float mu = s * 0.00390625f;
  const float a = v.x - mu, b = v.y - mu, c = v.z - mu, d = v.w - mu;
  float q = a * a + b * b + c * c + d * d;
#pragma unroll
  for (int off = 32; off > 0; off >>= 1) q += __shfl_xor(q, off, 64);
  const float rs = rsqrtf(q * 0.00390625f + 1e-5f);
  const int cb = l << 2;
  const float o0 = a * rs * in_elem(gamw, eoff + cb + 0, m) + in_elem(betw, eoff + cb + 0, m);
  const float o1 = b * rs * in_elem(gamw, eoff + cb + 1, m) + in_elem(betw, eoff + cb + 1, m);
  const float o2 = c * rs * in_elem(gamw, eoff + cb + 2, m) + in_elem(betw, eoff + cb + 2, m);
  const float o3 = d * rs * in_elem(gamw, eoff + cb + 3, m) + in_elem(betw, eoff + cb + 3, m);
  const u32 p0 = (u32)f2b(o0) | ((u32)f2b(o1) << 16);
  const u32 p1 = (u32)f2b(o2) | ((u32)f2b(o3) << 16);
  *(uint2*)((u16*)outp + (size_t)row * 256 + cb) = make_uint2(p0, p1);
}

// ---------------- bf16 MFMA GEMM: C[M,N] = A[M,K] @ Bt[N,K]^T + bias ----------------
// Tile TM x 128 (TM = 64 or 128), 4 waves (2x2; wave tile TM/2 x 64), 16x16x32 MFMA,
// global_load_lds width=16 staging.
// EPI: 0 = store bf16; 1 = GELU(exact)+store bf16;
//      2 = window-reverse(+shift) + fp32 residual add into outf;
//      3 = fp32 residual add into outf (identity rows);
//      4 = final: ((float*)outb)[.] = outf[.] + v  (outf read-only).
template <int EPI, int TM>
__global__ __launch_bounds__(256, (TM == 64 ? 4 : 2)) void k_gemm(
    const bf16* __restrict__ A, const bf16* __restrict__ Bt,
    const void* __restrict__ bias, bf16* __restrict__ outb,
    float* __restrict__ outf, const int* __restrict__ mode,
    int boff, int K, int N, int shift)
{
  constexpr int MI = TM / 32;   // acc rows per wave
  __shared__ __align__(16) bf16 As[TM * 32];
  __shared__ __align__(16) bf16 Bs[128 * 32];
  const int md = *mode;
  const int tid = threadIdx.x;
  const int l = tid & 63, wid = tid >> 6;
  const int wr = wid >> 1, wc = wid & 1;
  const int row0 = blockIdx.y * TM;
  const int col0 = blockIdx.x * 128;
  const int lrow = l >> 2;          // row within 16-row segment
  const int lkof = (l & 3) * 8;     // k-offset (8 bf16 = 16 B)

  floatx4 acc[MI][4];
#pragma unroll
  for (int mi = 0; mi < MI; ++mi)
#pragma unroll
    for (int ni = 0; ni < 4; ++ni)
      acc[mi][ni] = (floatx4){0.f, 0.f, 0.f, 0.f};

  for (int k0 = 0; k0 < K; k0 += 32) {
    __syncthreads();  // all waves done reading previous LDS tiles
#pragma unroll
    for (int c = 0; c < TM / 64; ++c) {
      const int seg = c * 4 + wid;  // TM/16 segments of 16 rows
      async16(A + (size_t)(row0 + seg * 16 + lrow) * K + (k0 + lkof), &As[seg * 512]);
    }
#pragma unroll
    for (int c = 0; c < 2; ++c) {
      const int seg = c * 4 + wid;
      async16(Bt + (size_t)(col0 + seg * 16 + lrow) * K + (k0 + lkof), &Bs[seg * 512]);
    }
    __syncthreads();  // vmcnt(0) drain before barrier -> staging complete

    short8 af[MI], bf8[4];
#pragma unroll
    for (int mi = 0; mi < MI; ++mi)
      af[mi] = *(const short8*)&As[(wr * (TM / 2) + mi * 16 + (l & 15)) * 32 + (l >> 4) * 8];
#pragma unroll
    for (int ni = 0; ni < 4; ++ni)
      bf8[ni] = *(const short8*)&Bs[(wc * 64 + ni * 16 + (l & 15)) * 32 + (l >> 4) * 8];
#pragma unroll
    for (int mi = 0; mi < MI; ++mi)
#pragma unroll
      for (int ni = 0; ni < 4; ++ni)
        acc[mi][ni] = __builtin_amdgcn_mfma_f32_16x16x32_bf16(af[mi], bf8[ni], acc[mi][ni], 0, 0, 0);
  }

  const int cl = l & 15, rq = l >> 4;  // C/D: col=lane&15, row=(lane>>4)*4+reg
#pragma unroll
  for (int mi = 0; mi < MI; ++mi) {
#pragma unroll
    for (int ni = 0; ni < 4; ++ni) {
      const int col = col0 + wc * 64 + ni * 16 + cl;
      const float bv = in_elem(bias, (size_t)boff + col, md);
#pragma unroll
      for (int r = 0; r < 4; ++r) {
        const int row = row0 + wr * (TM / 2) + mi * 16 + rq * 4 + r;
        float v = acc[mi][ni][r] + bv;
        if (EPI == 0) {
          ((u16*)outb)[(size_t)row * N + col] = f2b(v);
        } else if (EPI == 1) {
          v = 0.5f * v * (1.f + erff(v * 0.70710678118654752440f));
          ((u16*)outb)[(size_t)row * N + col] = f2b(v);
        } else if (EPI == 2) {
          const int t = row & 63, win = row >> 6;
          const int bb = win >> 6, wi = win & 63;
          int gh = ((wi >> 3) << 3) + (t >> 3);
          int gw = ((wi & 7) << 3) + (t & 7);
          gh = (gh + shift) & 63; gw = (gw + shift) & 63;
          outf[(((size_t)bb << 12) + (gh << 6) + gw) * 256 + col] += v;
        } else if (EPI == 3) {
          outf[(size_t)row * 256 + col] += v;
        } else {
          ((float*)outb)[(size_t)row * 256 + col] = outf[(size_t)row * 256 + col] + v;
        }
      }
    }
  }
}

// ---------------- windowed attention (MFMA; wave = window x head, 2 heads/wave) ----------------
__global__ __launch_bounds__(256, 2) void k_attn(
    const bf16* __restrict__ qkv, const void* __restrict__ rpb,
    bf16* __restrict__ outp, const int* __restrict__ mode, int eoff, int shifted)
{
  __shared__ __align__(16) u16 Pl[4][64][72];   // 36864 B
  __shared__ __align__(16) u16 Vt[4][32][72];   // 18432 B
  __shared__ float rpbs[4][228];                //  3648 B
  const int md = *mode;
  const int l = threadIdx.x & 63, w = threadIdx.x >> 6;
  const int cl = l & 15, qd = l >> 4;
  const int ko = qd * 8;
  const int win = blockIdx.x;
  const int wi = win & 63;
  const int whb = (wi >> 3) << 3, wwb = (wi & 7) << 3;
  const size_t rowbase = (size_t)win * 64 * 768;

  for (int hh = 0; hh < 2; ++hh) {
    const int h = w + hh * 4;
    for (int i = l; i < 225; i += 64)
      rpbs[w][i] = in_elem(rpb, (size_t)eoff + (size_t)i * 8 + h, md);
    {
      const u16* vrow = (const u16*)(qkv + rowbase + (size_t)l * 768 + 512 + h * 32);
#pragma unroll
      for (int n = 0; n < 32; ++n) Vt[w][n][l] = vrow[n];
    }
    short8 qf[4], kf[4];
#pragma unroll
    for (int t = 0; t < 4; ++t) {
      qf[t] = *(const short8*)(qkv + rowbase + (size_t)(t * 16 + cl) * 768 + h * 32 + ko);
      kf[t] = *(const short8*)(qkv + rowbase + (size_t)(t * 16 + cl) * 768 + 256 + h * 32 + ko);
    }
    __syncthreads();

    floatx4 S[4][4];
#pragma unroll
    for (int mi = 0; mi < 4; ++mi)
#pragma unroll
      for (int ni = 0; ni < 4; ++ni)
        S[mi][ni] = __builtin_amdgcn_mfma_f32_16x16x32_bf16(qf[mi], kf[ni], (floatx4){0.f, 0.f, 0.f, 0.f}, 0, 0, 0);

    int cty[4], ctx[4], clab[4];
#pragma unroll
    for (int ni = 0; ni < 4; ++ni) {
      const int ct = ni * 16 + cl;
      cty[ni] = ct >> 3; ctx[ni] = ct & 7;
      clab[ni] = shifted ? (swlab(whb + cty[ni]) * 3 + swlab(wwb + ctx[ni])) : 0;
    }

    float invs[4][4];
#pragma unroll
    for (int mi = 0; mi < 4; ++mi) {
#pragma unroll
      for (int r = 0; r < 4; ++r) {
        const int rt = mi * 16 + qd * 4 + r;
        const int rty = rt >> 3, rtx = rt & 7;
        const int rlab = shifted ? (swlab(whb + rty) * 3 + swlab(wwb + rtx)) : 0;
        float sv[4];
#pragma unroll
        for (int ni = 0; ni < 4; ++ni) {
          float x = S[mi][ni][r] * 0.17677669529663687f;
          x += rpbs[w][(rty - cty[ni] + 7) * 15 + (rtx - ctx[ni] + 7)];
          if (shifted && (rlab != clab[ni])) x -= 100.f;
          sv[ni] = x;
        }
        float mx = fmaxf(fmaxf(sv[0], sv[1]), fmaxf(sv[2], sv[3]));
        mx = fmaxf(mx, __shfl_xor(mx, 1, 64));
        mx = fmaxf(mx, __shfl_xor(mx, 2, 64));
        mx = fmaxf(mx, __shfl_xor(mx, 4, 64));
        mx = fmaxf(mx, __shfl_xor(mx, 8, 64));
        float sum = 0.f;
#pragma unroll
        for (int ni = 0; ni < 4; ++ni) { sv[ni] = __expf(sv[ni] - mx); sum += sv[ni]; }
        sum += __shfl_xor(sum, 1, 64);
        sum += __shfl_xor(sum, 2, 64);
        sum += __shfl_xor(sum, 4, 64);
        sum += __shfl_xor(sum, 8, 64);
        invs[mi][r] = 1.f / sum;
#pragma unroll
        for (int ni = 0; ni < 4; ++ni) Pl[w][rt][ni * 16 + cl] = f2b(sv[ni]);
      }
    }
    __syncthreads();

    floatx4 O[4][2];
#pragma unroll
    for (int mi = 0; mi < 4; ++mi)
#pragma unroll
      for (int nv = 0; nv < 2; ++nv)
        O[mi][nv] = (floatx4){0.f, 0.f, 0.f, 0.f};
    short8 vf[2][2];
#pragma unroll
    for (int nv = 0; nv < 2; ++nv)
#pragma unroll
      for (int kk = 0; kk < 2; ++kk)
        vf[nv][kk] = *(const short8*)&Vt[w][nv * 16 + cl][kk * 32 + ko];
#pragma unroll
    for (int mi = 0; mi < 4; ++mi) {
      const short8 pf0 = *(const short8*)&Pl[w][mi * 16 + cl][ko];
      const short8 pf1 = *(const short8*)&Pl[w][mi * 16 + cl][32 + ko];
#pragma unroll
      for (int nv = 0; nv < 2; ++nv) {
        O[mi][nv] = __builtin_amdgcn_mfma_f32_16x16x32_bf16(pf0, vf[nv][0], O[mi][nv], 0, 0, 0);
        O[mi][nv] = __builtin_amdgcn_mfma_f32_16x16x32_bf16(pf1, vf[nv][1], O[mi][nv], 0, 0, 0);
      }
    }

#pragma unroll
    for (int mi = 0; mi < 4; ++mi)
#pragma unroll
      for (int nv = 0; nv < 2; ++nv)
#pragma unroll
        for (int r = 0; r < 4; ++r) {
          const int row = mi * 16 + qd * 4 + r;
          ((u16*)outp)[((size_t)win * 64 + row) * 256 + h * 32 + nv * 16 + cl] =
              f2b(O[mi][nv][r] * invs[mi][r]);
        }
    __syncthreads();
  }
}

// ---------------- host launcher ----------------
extern "C" void kernel_launch(void* const* d_in, const int* in_sizes, int n_in,
                              void* d_out, int out_size, void* d_ws, size_t ws_size,
                              hipStream_t stream) {
  (void)in_sizes; (void)n_in; (void)out_size; (void)ws_size;
  const void* x_in   = d_in[0];
  const void* qkv_w  = d_in[1];
  const void* qkv_b  = d_in[2];
  const void* proj_w = d_in[3];
  const void* proj_b = d_in[4];
  const void* ln1_g  = d_in[5];
  const void* ln1_b  = d_in[6];
  const void* ln2_g  = d_in[7];
  const void* ln2_b  = d_in[8];
  const void* fc1_w  = d_in[9];
  const void* fc1_b  = d_in[10];
  const void* fc2_w  = d_in[11];
  const void* fc2_b  = d_in[12];
  const void* rpb    = d_in[13];

  char* ws = (char*)d_ws;
  float* xf  = (float*)ws;                   // 32 MiB
  bf16* bufH = (bf16*)(ws + 33554432);       // 64 MiB fc1 hidden
  bf16* bufQ = (bf16*)(ws + 100663296);      // 48 MiB qkv
  bf16* bufB = (bf16*)(ws + 150994944);      // 16 MiB LN out / attn out
  bf16* wT   = (bf16*)(ws + 167772160);      // 3 MiB
  int* mode  = (int*)(ws + 170917888);       // 4 B

  k_detect<<<1, 1, 0, stream>>>((const u32*)ln1_g, mode);
  k_ingest<<<16384, 256, 0, stream>>>(x_in, (float2*)xf, mode, 4194304);

  // transposed weights per depth (batched over depth inside kernel):
  // qkvT[768][256] @0, projT[256][256] @196608, fc1T[1024][256] @262144, fc2T[256][1024] @524288
  k_transpose<<<768, 256, 0, stream>>>(qkv_w,  wT,          mode, 196608, 786432, 256, 768, 768);
  k_transpose<<<256, 256, 0, stream>>>(proj_w, wT + 196608, mode, 65536, 786432, 256, 256, 256);
  k_transpose<<<1024, 256, 0, stream>>>(fc1_w, wT + 262144, mode, 262144, 786432, 256, 1024, 1024);
  k_transpose<<<1024, 256, 0, stream>>>(fc2_w, wT + 524288, mode, 262144, 786432, 1024, 256, 256);

  for (int i = 0; i < 2; ++i) {
    const int shift = i ? 4 : 0;
    bf16* base  = wT + (size_t)i * 786432;
    bf16* qkvT  = base;
    bf16* projT = base + 196608;
    bf16* fc1T  = base + 262144;
    bf16* fc2T  = base + 524288;

    // LN1 + (shift) + window partition -> bufB
    k_ln<<<8192, 256, 0, stream>>>(xf, ln1_g, ln1_b, bufB, mode, i * 256, 1, shift);
    // QKV: bufQ[32768,768] = bufB @ qkv_w + b
    k_gemm<0, 128><<<dim3(6, 256), 256, 0, stream>>>(bufB, qkvT, qkv_b, bufQ, nullptr, mode, i * 768, 256, 768, 0);
    // windowed attention: bufQ -> bufB
    k_attn<<<512, 256, 0, stream>>>(bufQ, rpb, bufB, mode, i * 1800, i);
    // proj + window-reverse + unshift + residual add into xf (TM=64: 1024 blocks)
    k_gemm<2, 64><<<dim3(2, 512), 256, 0, stream>>>(bufB, projT, proj_b, nullptr, xf, mode, i * 256, 256, 256, shift);
    // LN2 -> bufB
    k_ln<<<8192, 256, 0, stream>>>(xf, ln2_g, ln2_b, bufB, mode, i * 256, 0, 0);
    // FC1: bufH[32768,1024] = GELU(bufB @ fc1_w + b)
    k_gemm<1, 128><<<dim3(8, 256), 256, 0, stream>>>(bufB, fc1T, fc1_b, bufH, nullptr, mode, i * 1024, 256, 1024, 0);
    // FC2 (K=1024) + residual; depth 1 writes final fp32 output directly
    if (i == 0)
      k_gemm<3, 64><<<dim3(2, 512), 256, 0, stream>>>(bufH, fc2T, fc2_b, nullptr, xf, mode, i * 256, 1024, 256, 0);
    else
      k_gemm<4, 64><<<dim3(2, 512), 256, 0, stream>>>(bufH, fc2T, fc2_b, (bf16*)d_out, xf, mode, i * 256, 1024, 256, 0);
  }
}

// Round 8
// 527.104 us; speedup vs baseline: 1.4428x; 1.0218x over previous
//
#include <hip/hip_runtime.h>
#include <hip/hip_bf16.h>

// SwinTransformerEncoder on gfx950.
// H=W=64, C=256, HEADS=8 (d=32), WS=8, N=64 tok/window, NW=64, B=8, DEPTH=2, HIDDEN=1024.
// Inputs fp32 (runtime probe also supports bf16-cast). OUTPUT fp32. Residual fp32 in ws.
// R8: (1) k_gemm stages TWO BK=32 slices per barrier pair (halves vmcnt(0)+barrier
//     drains; each slice keeps the m97-proven LDS layout); (2) coalesced 32x32-tile
//     weight transpose.
//
// Workspace (~171 MiB of 256 MiB):
//   xf   fp32 [8*4096*256]   @ 0          (32 MiB)  residual stream
//   bufH bf16 [32768*1024]   @ 33554432   (64 MiB)  fc1 hidden
//   bufQ bf16 [32768*768]    @ 100663296  (48 MiB)  qkv
//   bufB bf16 [32768*256]    @ 150994944  (16 MiB)  LN out / attn out
//   wT   bf16 [2*786432]     @ 167772160  (3 MiB)   transposed weights
//   mode int                 @ 170917888  (4 B)     input-dtype flag (1=bf16, 0=fp32)

typedef __hip_bfloat16 bf16;
typedef unsigned short u16;
typedef unsigned int u32;
typedef short short8 __attribute__((ext_vector_type(8)));
typedef float floatx4 __attribute__((ext_vector_type(4)));

#define DEVI static __device__ __forceinline__

DEVI float lo16(u32 u) { union { u32 i; float f; } x; x.i = u << 16; return x.f; }
DEVI float hi16(u32 u) { union { u32 i; float f; } x; x.i = u & 0xffff0000u; return x.f; }
DEVI float b2f(u16 u) { union { u32 i; float f; } x; x.i = ((u32)u) << 16; return x.f; }
DEVI u16 f2b(float f) {  // round-to-nearest-even
  union { float f; u32 i; } x; x.f = f;
  u32 r = x.i + 0x7fffu + ((x.i >> 16) & 1u);
  return (u16)(r >> 16);
}
DEVI float in_elem(const void* p, size_t i, int m) {
  return m ? b2f(((const u16*)p)[i]) : ((const float*)p)[i];
}
DEVI int swlab(int g) { return (g < 56) ? 0 : (g < 60 ? 1 : 2); }

DEVI void async16(const bf16* g, bf16* l) {
  __builtin_amdgcn_global_load_lds((const __attribute__((address_space(1))) u32*)g,
                                   (__attribute__((address_space(3))) u32*)l, 16, 0, 0);
}

// ---------------- dtype probe (ln1_g is all-ones) ----------------
__global__ void k_detect(const u32* __restrict__ ln1g, int* __restrict__ mode) {
  if (threadIdx.x == 0 && blockIdx.x == 0)
    *mode = (ln1g[0] == 0x3F803F80u) ? 1 : 0;
}

// ---------------- ingest x -> fp32 residual ----------------
__global__ void k_ingest(const void* __restrict__ xin, float2* __restrict__ out,
                         const int* __restrict__ mode, int n2) {
  const int i = blockIdx.x * 256 + threadIdx.x;
  if (i >= n2) return;
  if (*mode) { const u32 u = ((const u32*)xin)[i]; out[i] = make_float2(lo16(u), hi16(u)); }
  else out[i] = ((const float2*)xin)[i];
}

// ---------------- coalesced weight transpose: dst[c][r] = src[r][c], both depths ----------
// 32x32 LDS tiles (+1 pad). src slice d at d*estride (elements), dst slice at d*dstride.
__global__ __launch_bounds__(256) void k_transpose(
    const void* __restrict__ src, bf16* __restrict__ dst,
    const int* __restrict__ mode, int estride, int dstride, int R, int Cn) {
  __shared__ float T[32][33];
  const int m = *mode;
  const int tx = threadIdx.x & 31, ty = threadIdx.x >> 5;  // ty in 0..7
  const int bc = blockIdx.x << 5, br = blockIdx.y << 5;
  for (int d = 0; d < 2; ++d) {
    __syncthreads();
#pragma unroll
    for (int dy = 0; dy < 4; ++dy) {
      const int r = br + ty + dy * 8;
      T[ty + dy * 8][tx] = in_elem(src, (size_t)d * estride + (size_t)r * Cn + bc + tx, m);
    }
    __syncthreads();
#pragma unroll
    for (int dy = 0; dy < 4; ++dy) {
      const int c = bc + ty + dy * 8;
      ((u16*)dst)[(size_t)d * dstride + (size_t)c * R + br + tx] = f2b(T[tx][ty + dy * 8]);
    }
  }
}

// ---------------- LayerNorm (+ optional shift + window partition) ----------------
__global__ __launch_bounds__(256) void k_ln(const float* __restrict__ xf,
    const void* __restrict__ gamw, const void* __restrict__ betw,
    bf16* __restrict__ outp, const int* __restrict__ mode, int eoff,
    int windowed, int shift)
{
  const int m = *mode;
  const int l = threadIdx.x & 63, w = threadIdx.x >> 6;
  const int row = blockIdx.x * 4 + w;
  int srow;
  if (windowed) {
    const int t = row & 63, win = row >> 6;
    const int bb = win >> 6, wi = win & 63;
    const int gh = ((wi >> 3) << 3) + (t >> 3);
    const int gw = ((wi & 7) << 3) + (t & 7);
    const int sh = (gh + shift) & 63, sw = (gw + shift) & 63;
    srow = (bb << 12) + (sh << 6) + sw;
  } else {
    srow = row;
  }
  const float4 v = ((const float4*)(xf + (size_t)srow * 256))[l];
  float s = v.x + v.y + v.z + v.w;
#pragma unroll
  for (int off = 32; off > 0; off >>= 1) s += __shfl_xor(s, off, 64);
  const float mu = s * 0.00390625f;
  const float a = v.x - mu, b = v.y - mu, c = v.z - mu, d = v.w - mu;
  float q = a * a + b * b + c * c + d * d;
#pragma unroll
  for (int off = 32; off > 0; off >>= 1) q += __shfl_xor(q, off, 64);
  const float rs = rsqrtf(q * 0.00390625f + 1e-5f);
  const int cb = l << 2;
  const float o0 = a * rs * in_elem(gamw, eoff + cb + 0, m) + in_elem(betw, eoff + cb + 0, m);
  const float o1 = b * rs * in_elem(gamw, eoff + cb + 1, m) + in_elem(betw, eoff + cb + 1, m);
  const float o2 = c * rs * in_elem(gamw, eoff + cb + 2, m) + in_elem(betw, eoff + cb + 2, m);
  const float o3 = d * rs * in_elem(gamw, eoff + cb + 3, m) + in_elem(betw, eoff + cb + 3, m);
  const u32 p0 = (u32)f2b(o0) | ((u32)f2b(o1) << 16);
  const u32 p1 = (u32)f2b(o2) | ((u32)f2b(o3) << 16);
  *(uint2*)((u16*)outp + (size_t)row * 256 + cb) = make_uint2(p0, p1);
}

// ---------------- bf16 MFMA GEMM: C[M,N] = A[M,K] @ Bt[N,K]^T + bias ----------------
// Tile TM x 128 (TM = 64 or 128), 4 waves (2x2; wave tile TM/2 x 64), 16x16x32 MFMA.
// K-loop: TWO BK=32 slices staged per barrier pair (async16, m97 layout per slice).
// EPI: 0 = store bf16; 1 = GELU(exact)+store bf16;
//      2 = window-reverse(+shift) + fp32 residual add into outf;
//      3 = fp32 residual add into outf (identity rows);
//      4 = final: ((float*)outb)[.] = outf[.] + v  (outf read-only).
template <int EPI, int TM>
__global__ __launch_bounds__(256, (TM == 64 ? 4 : 2)) void k_gemm(
    const bf16* __restrict__ A, const bf16* __restrict__ Bt,
    const void* __restrict__ bias, bf16* __restrict__ outb,
    float* __restrict__ outf, const int* __restrict__ mode,
    int boff, int K, int N, int shift)
{
  constexpr int MI = TM / 32;   // acc rows per wave
  __shared__ __align__(16) bf16 As[2][TM * 32];
  __shared__ __align__(16) bf16 Bs[2][128 * 32];
  const int md = *mode;
  const int tid = threadIdx.x;
  const int l = tid & 63, wid = tid >> 6;
  const int wr = wid >> 1, wc = wid & 1;
  const int row0 = blockIdx.y * TM;
  const int col0 = blockIdx.x * 128;
  const int lrow = l >> 2;          // row within 16-row segment
  const int lkof = (l & 3) * 8;     // k-offset (8 bf16 = 16 B)

  floatx4 acc[MI][4];
#pragma unroll
  for (int mi = 0; mi < MI; ++mi)
#pragma unroll
    for (int ni = 0; ni < 4; ++ni)
      acc[mi][ni] = (floatx4){0.f, 0.f, 0.f, 0.f};

  for (int k0 = 0; k0 < K; k0 += 64) {
    __syncthreads();  // all waves done reading previous LDS tiles
#pragma unroll
    for (int s = 0; s < 2; ++s) {
      const int kk = k0 + s * 32 + lkof;
#pragma unroll
      for (int c = 0; c < TM / 64; ++c) {
        const int seg = c * 4 + wid;  // segments of 16 rows
        async16(A + (size_t)(row0 + seg * 16 + lrow) * K + kk, &As[s][seg * 512]);
      }
#pragma unroll
      for (int c = 0; c < 2; ++c) {
        const int seg = c * 4 + wid;
        async16(Bt + (size_t)(col0 + seg * 16 + lrow) * K + kk, &Bs[s][seg * 512]);
      }
    }
    __syncthreads();  // vmcnt(0) drain -> both slices staged

#pragma unroll
    for (int s = 0; s < 2; ++s) {
      short8 af[MI], bf8[4];
#pragma unroll
      for (int mi = 0; mi < MI; ++mi)
        af[mi] = *(const short8*)&As[s][(wr * (TM / 2) + mi * 16 + (l & 15)) * 32 + (l >> 4) * 8];
#pragma unroll
      for (int ni = 0; ni < 4; ++ni)
        bf8[ni] = *(const short8*)&Bs[s][(wc * 64 + ni * 16 + (l & 15)) * 32 + (l >> 4) * 8];
#pragma unroll
      for (int mi = 0; mi < MI; ++mi)
#pragma unroll
        for (int ni = 0; ni < 4; ++ni)
          acc[mi][ni] = __builtin_amdgcn_mfma_f32_16x16x32_bf16(af[mi], bf8[ni], acc[mi][ni], 0, 0, 0);
    }
  }

  const int cl = l & 15, rq = l >> 4;  // C/D: col=lane&15, row=(lane>>4)*4+reg
#pragma unroll
  for (int mi = 0; mi < MI; ++mi) {
#pragma unroll
    for (int ni = 0; ni < 4; ++ni) {
      const int col = col0 + wc * 64 + ni * 16 + cl;
      const float bv = in_elem(bias, (size_t)boff + col, md);
#pragma unroll
      for (int r = 0; r < 4; ++r) {
        const int row = row0 + wr * (TM / 2) + mi * 16 + rq * 4 + r;
        float v = acc[mi][ni][r] + bv;
        if (EPI == 0) {
          ((u16*)outb)[(size_t)row * N + col] = f2b(v);
        } else if (EPI == 1) {
          v = 0.5f * v * (1.f + erff(v * 0.70710678118654752440f));
          ((u16*)outb)[(size_t)row * N + col] = f2b(v);
        } else if (EPI == 2) {
          const int t = row & 63, win = row >> 6;
          const int bb = win >> 6, wi = win & 63;
          int gh = ((wi >> 3) << 3) + (t >> 3);
          int gw = ((wi & 7) << 3) + (t & 7);
          gh = (gh + shift) & 63; gw = (gw + shift) & 63;
          outf[(((size_t)bb << 12) + (gh << 6) + gw) * 256 + col] += v;
        } else if (EPI == 3) {
          outf[(size_t)row * 256 + col] += v;
        } else {
          ((float*)outb)[(size_t)row * 256 + col] = outf[(size_t)row * 256 + col] + v;
        }
      }
    }
  }
}

// ---------------- windowed attention (MFMA; wave = window x head, 2 heads/wave) ----------------
__global__ __launch_bounds__(256, 2) void k_attn(
    const bf16* __restrict__ qkv, const void* __restrict__ rpb,
    bf16* __restrict__ outp, const int* __restrict__ mode, int eoff, int shifted)
{
  __shared__ __align__(16) u16 Pl[4][64][72];   // 36864 B
  __shared__ __align__(16) u16 Vt[4][32][72];   // 18432 B
  __shared__ float rpbs[4][228];                //  3648 B
  const int md = *mode;
  const int l = threadIdx.x & 63, w = threadIdx.x >> 6;
  const int cl = l & 15, qd = l >> 4;
  const int ko = qd * 8;
  const int win = blockIdx.x;
  const int wi = win & 63;
  const int whb = (wi >> 3) << 3, wwb = (wi & 7) << 3;
  const size_t rowbase = (size_t)win * 64 * 768;

  for (int hh = 0; hh < 2; ++hh) {
    const int h = w + hh * 4;
    for (int i = l; i < 225; i += 64)
      rpbs[w][i] = in_elem(rpb, (size_t)eoff + (size_t)i * 8 + h, md);
    {
      const u16* vrow = (const u16*)(qkv + rowbase + (size_t)l * 768 + 512 + h * 32);
#pragma unroll
      for (int n = 0; n < 32; ++n) Vt[w][n][l] = vrow[n];
    }
    short8 qf[4], kf[4];
#pragma unroll
    for (int t = 0; t < 4; ++t) {
      qf[t] = *(const short8*)(qkv + rowbase + (size_t)(t * 16 + cl) * 768 + h * 32 + ko);
      kf[t] = *(const short8*)(qkv + rowbase + (size_t)(t * 16 + cl) * 768 + 256 + h * 32 + ko);
    }
    __syncthreads();

    floatx4 S[4][4];
#pragma unroll
    for (int mi = 0; mi < 4; ++mi)
#pragma unroll
      for (int ni = 0; ni < 4; ++ni)
        S[mi][ni] = __builtin_amdgcn_mfma_f32_16x16x32_bf16(qf[mi], kf[ni], (floatx4){0.f, 0.f, 0.f, 0.f}, 0, 0, 0);

    int cty[4], ctx[4], clab[4];
#pragma unroll
    for (int ni = 0; ni < 4; ++ni) {
      const int ct = ni * 16 + cl;
      cty[ni] = ct >> 3; ctx[ni] = ct & 7;
      clab[ni] = shifted ? (swlab(whb + cty[ni]) * 3 + swlab(wwb + ctx[ni])) : 0;
    }

    float invs[4][4];
#pragma unroll
    for (int mi = 0; mi < 4; ++mi) {
#pragma unroll
      for (int r = 0; r < 4; ++r) {
        const int rt = mi * 16 + qd * 4 + r;
        const int rty = rt >> 3, rtx = rt & 7;
        const int rlab = shifted ? (swlab(whb + rty) * 3 + swlab(wwb + rtx)) : 0;
        float sv[4];
#pragma unroll
        for (int ni = 0; ni < 4; ++ni) {
          float x = S[mi][ni][r] * 0.17677669529663687f;
          x += rpbs[w][(rty - cty[ni] + 7) * 15 + (rtx - ctx[ni] + 7)];
          if (shifted && (rlab != clab[ni])) x -= 100.f;
          sv[ni] = x;
        }
        float mx = fmaxf(fmaxf(sv[0], sv[1]), fmaxf(sv[2], sv[3]));
        mx = fmaxf(mx, __shfl_xor(mx, 1, 64));
        mx = fmaxf(mx, __shfl_xor(mx, 2, 64));
        mx = fmaxf(mx, __shfl_xor(mx, 4, 64));
        mx = fmaxf(mx, __shfl_xor(mx, 8, 64));
        float sum = 0.f;
#pragma unroll
        for (int ni = 0; ni < 4; ++ni) { sv[ni] = __expf(sv[ni] - mx); sum += sv[ni]; }
        sum += __shfl_xor(sum, 1, 64);
        sum += __shfl_xor(sum, 2, 64);
        sum += __shfl_xor(sum, 4, 64);
        sum += __shfl_xor(sum, 8, 64);
        invs[mi][r] = 1.f / sum;
#pragma unroll
        for (int ni = 0; ni < 4; ++ni) Pl[w][rt][ni * 16 + cl] = f2b(sv[ni]);
      }
    }
    __syncthreads();

    floatx4 O[4][2];
#pragma unroll
    for (int mi = 0; mi < 4; ++mi)
#pragma unroll
      for (int nv = 0; nv < 2; ++nv)
        O[mi][nv] = (floatx4){0.f, 0.f, 0.f, 0.f};
    short8 vf[2][2];
#pragma unroll
    for (int nv = 0; nv < 2; ++nv)
#pragma unroll
      for (int kk = 0; kk < 2; ++kk)
        vf[nv][kk] = *(const short8*)&Vt[w][nv * 16 + cl][kk * 32 + ko];
#pragma unroll
    for (int mi = 0; mi < 4; ++mi) {
      const short8 pf0 = *(const short8*)&Pl[w][mi * 16 + cl][ko];
      const short8 pf1 = *(const short8*)&Pl[w][mi * 16 + cl][32 + ko];
#pragma unroll
      for (int nv = 0; nv < 2; ++nv) {
        O[mi][nv] = __builtin_amdgcn_mfma_f32_16x16x32_bf16(pf0, vf[nv][0], O[mi][nv], 0, 0, 0);
        O[mi][nv] = __builtin_amdgcn_mfma_f32_16x16x32_bf16(pf1, vf[nv][1], O[mi][nv], 0, 0, 0);
      }
    }

#pragma unroll
    for (int mi = 0; mi < 4; ++mi)
#pragma unroll
      for (int nv = 0; nv < 2; ++nv)
#pragma unroll
        for (int r = 0; r < 4; ++r) {
          const int row = mi * 16 + qd * 4 + r;
          ((u16*)outp)[((size_t)win * 64 + row) * 256 + h * 32 + nv * 16 + cl] =
              f2b(O[mi][nv][r] * invs[mi][r]);
        }
    __syncthreads();
  }
}

// ---------------- host launcher ----------------
extern "C" void kernel_launch(void* const* d_in, const int* in_sizes, int n_in,
                              void* d_out, int out_size, void* d_ws, size_t ws_size,
                              hipStream_t stream) {
  (void)in_sizes; (void)n_in; (void)out_size; (void)ws_size;
  const void* x_in   = d_in[0];
  const void* qkv_w  = d_in[1];
  const void* qkv_b  = d_in[2];
  const void* proj_w = d_in[3];
  const void* proj_b = d_in[4];
  const void* ln1_g  = d_in[5];
  const void* ln1_b  = d_in[6];
  const void* ln2_g  = d_in[7];
  const void* ln2_b  = d_in[8];
  const void* fc1_w  = d_in[9];
  const void* fc1_b  = d_in[10];
  const void* fc2_w  = d_in[11];
  const void* fc2_b  = d_in[12];
  const void* rpb    = d_in[13];

  char* ws = (char*)d_ws;
  float* xf  = (float*)ws;                   // 32 MiB
  bf16* bufH = (bf16*)(ws + 33554432);       // 64 MiB fc1 hidden
  bf16* bufQ = (bf16*)(ws + 100663296);      // 48 MiB qkv
  bf16* bufB = (bf16*)(ws + 150994944);      // 16 MiB LN out / attn out
  bf16* wT   = (bf16*)(ws + 167772160);      // 3 MiB
  int* mode  = (int*)(ws + 170917888);       // 4 B

  k_detect<<<1, 1, 0, stream>>>((const u32*)ln1_g, mode);
  k_ingest<<<16384, 256, 0, stream>>>(x_in, (float2*)xf, mode, 4194304);

  // transposed weights per depth (batched over depth inside kernel):
  // qkvT[768][256] @0, projT[256][256] @196608, fc1T[1024][256] @262144, fc2T[256][1024] @524288
  k_transpose<<<dim3(24, 8), 256, 0, stream>>>(qkv_w,  wT,          mode, 196608, 786432, 256, 768);
  k_transpose<<<dim3(8, 8), 256, 0, stream>>>(proj_w, wT + 196608, mode, 65536, 786432, 256, 256);
  k_transpose<<<dim3(32, 8), 256, 0, stream>>>(fc1_w, wT + 262144, mode, 262144, 786432, 256, 1024);
  k_transpose<<<dim3(8, 32), 256, 0, stream>>>(fc2_w, wT + 524288, mode, 262144, 786432, 1024, 256);

  for (int i = 0; i < 2; ++i) {
    const int shift = i ? 4 : 0;
    bf16* base  = wT + (size_t)i * 786432;
    bf16* qkvT  = base;
    bf16* projT = base + 196608;
    bf16* fc1T  = base + 262144;
    bf16* fc2T  = base + 524288;

    // LN1 + (shift) + window partition -> bufB
    k_ln<<<8192, 256, 0, stream>>>(xf, ln1_g, ln1_b, bufB, mode, i * 256, 1, shift);
    // QKV: bufQ[32768,768] = bufB @ qkv_w + b
    k_gemm<0, 128><<<dim3(6, 256), 256, 0, stream>>>(bufB, qkvT, qkv_b, bufQ, nullptr, mode, i * 768, 256, 768, 0);
    // windowed attention: bufQ -> bufB
    k_attn<<<512, 256, 0, stream>>>(bufQ, rpb, bufB, mode, i * 1800, i);
    // proj + window-reverse + unshift + residual add into xf (TM=64: 1024 blocks)
    k_gemm<2, 64><<<dim3(2, 512), 256, 0, stream>>>(bufB, projT, proj_b, nullptr, xf, mode, i * 256, 256, 256, shift);
    // LN2 -> bufB
    k_ln<<<8192, 256, 0, stream>>>(xf, ln2_g, ln2_b, bufB, mode, i * 256, 0, 0);
    // FC1: bufH[32768,1024] = GELU(bufB @ fc1_w + b)
    k_gemm<1, 128><<<dim3(8, 256), 256, 0, stream>>>(bufB, fc1T, fc1_b, bufH, nullptr, mode, i * 1024, 256, 1024, 0);
    // FC2 (K=1024) + residual; depth 1 writes final fp32 output directly
    if (i == 0)
      k_gemm<3, 64><<<dim3(2, 512), 256, 0, stream>>>(bufH, fc2T, fc2_b, nullptr, xf, mode, i * 256, 1024, 256, 0);
    else
      k_gemm<4, 64><<<dim3(2, 512), 256, 0, stream>>>(bufH, fc2T, fc2_b, (bf16*)d_out, xf, mode, i * 256, 1024, 256, 0);
  }
}